// Round 1
// baseline (771.104 us; speedup 1.0000x reference)
//
#include <hip/hip_runtime.h>

// AP (average precision @ IoU 0.5/0.75) for B=256, N=4000, G=50.
// Strategy: greedy TP matching per (batch,thr) -> <=12800 TP elements per thr;
// exact stable-descending-sort ranks of TPs via 65536-bucket counting sort of
// the 1.024M confidences; AP from TP ranks only (suffix-max of precision is
// attained at TP positions). No full argsort needed.

#define B_ 256
#define N_ 4000
#define G_ 50
#define M_ (B_ * N_)        // 1,024,000 proposals total
#define NL_ (B_ * G_)       // 12,800 labels total (= n_labels)
#define SLOTS 16            // ceil(N_/256)
#define NBKT 65536

__device__ __forceinline__ unsigned bucket_of(float c) {
    // conf in [0,1); uniform buckets, weakly monotone in c (rounding-safe clamp)
    unsigned b = (unsigned)(c * 65536.0f);
    return b > 65535u ? 65535u : b;
}

// ---- Phase 1: greedy matching. One block per (thr, batch). ----------------
__global__ __launch_bounds__(256) void tp_kernel(
    const float* __restrict__ seg,   // [B,N,2]
    const float* __restrict__ gts,   // [B,G,2]
    int* __restrict__ tpCount,       // [2], pre-zeroed
    int* __restrict__ tpIdx)         // [2][NL_]
{
    const int tid = threadIdx.x;
    const int b = blockIdx.x & 255;
    const int thr_i = blockIdx.x >> 8;
    const float thr = thr_i ? 0.75f : 0.5f;

    float amin[SLOTS], amax[SLOTS];
    const float2* sb = (const float2*)(seg + (size_t)b * (N_ * 2));
    #pragma unroll
    for (int s = 0; s < SLOTS; ++s) {
        int n = s * 256 + tid;
        if (n < N_) { float2 v = sb[n]; amin[s] = v.x; amax[s] = v.y; }
        else { amin[s] = 1e9f; amax[s] = 1e9f; }   // zero-length far away -> iou 0
    }

    unsigned used = 0u;
    __shared__ int lred[4];
    __shared__ int winner;
    const float* gb = gts + (size_t)b * (G_ * 2);

    for (int g = 0; g < G_; ++g) {
        float gmin = gb[2 * g], gmax = gb[2 * g + 1];
        float glen = gmax - gmin;
        int bestS = 1000;
        #pragma unroll
        for (int s = SLOTS - 1; s >= 0; --s) {   // descending: final = smallest s
            float inter = fminf(amax[s], gmax) - fmaxf(amin[s], gmin);
            inter = fmaxf(inter, 0.0f);
            float uni = (amax[s] - amin[s]) + glen - inter;  // same op order as ref
            float iou = inter / uni;
            if (!(used & (1u << s)) && iou > thr) bestS = s;
        }
        int best = (bestS < 1000) ? bestS * 256 + tid : 0x7FFFFFFF;
        #pragma unroll
        for (int off = 32; off >= 1; off >>= 1)
            best = min(best, __shfl_down(best, off, 64));
        if ((tid & 63) == 0) lred[tid >> 6] = best;
        __syncthreads();
        if (tid == 0) winner = min(min(lred[0], lred[1]), min(lred[2], lred[3]));
        __syncthreads();
        int w = winner;
        if (w != 0x7FFFFFFF && (w & 255) == tid) used |= 1u << (w >> 8);
        // no 3rd barrier needed: next lred write happens only after everyone
        // passes the 2nd barrier, and winner(g+1) only after the next 1st barrier
    }

    #pragma unroll
    for (int s = 0; s < SLOTS; ++s) {
        if (used & (1u << s)) {
            int pos = atomicAdd(&tpCount[thr_i], 1);
            tpIdx[thr_i * NL_ + pos] = b * N_ + (s * 256 + tid);
        }
    }
}

// ---- Phase 2a: histogram over confidences ---------------------------------
__global__ void hist_kernel(const float* __restrict__ conf, unsigned* __restrict__ hist) {
    int i = blockIdx.x * blockDim.x + threadIdx.x;
    if (i < M_) atomicAdd(&hist[bucket_of(conf[i])], 1u);
}

// ---- Phase 2b: exclusive scan of 65536 bins, single block -----------------
__global__ __launch_bounds__(1024) void scan_kernel(
    const unsigned* __restrict__ hist, unsigned* __restrict__ start,
    unsigned* __restrict__ cursor)
{
    __shared__ unsigned part[1024];
    int t = threadIdx.x;
    unsigned loc[64];
    unsigned s = 0;
    for (int k = 0; k < 64; ++k) { loc[k] = s; s += hist[t * 64 + k]; }
    part[t] = s;
    __syncthreads();
    for (int off = 1; off < 1024; off <<= 1) {   // inclusive Hillis-Steele
        unsigned add = (t >= off) ? part[t - off] : 0u;
        unsigned v = part[t];
        __syncthreads();
        part[t] = v + add;
        __syncthreads();
    }
    unsigned base = (t == 0) ? 0u : part[t - 1];
    for (int k = 0; k < 64; ++k) {
        unsigned st = base + loc[k];
        start[t * 64 + k] = st;
        cursor[t * 64 + k] = st;
    }
}

// ---- Phase 2c: scatter into bucket-grouped order --------------------------
__global__ void scatter_kernel(const float* __restrict__ conf,
                               unsigned* __restrict__ cursor,
                               float* __restrict__ sConf,
                               unsigned* __restrict__ sIdx)
{
    int i = blockIdx.x * blockDim.x + threadIdx.x;
    if (i < M_) {
        float c = conf[i];
        unsigned b = bucket_of(c);
        unsigned pos = atomicAdd(&cursor[b], 1u);
        sConf[pos] = c;
        sIdx[pos] = (unsigned)i;
    }
}

// ---- Phase 2d: exact rank of each TP (stable descending order) ------------
__global__ void rank_kernel(const float* __restrict__ conf,
                            const int* __restrict__ tpCount,
                            const int* __restrict__ tpIdx,
                            const unsigned* __restrict__ hist,
                            const unsigned* __restrict__ start,
                            const float* __restrict__ sConf,
                            const unsigned* __restrict__ sIdx,
                            int* __restrict__ tpRank)
{
    int thr_i = blockIdx.y;
    int t = blockIdx.x * blockDim.x + threadIdx.x;
    if (t >= tpCount[thr_i]) return;
    int e = tpIdx[thr_i * NL_ + t];
    float c = conf[e];
    unsigned b = bucket_of(c);
    unsigned lo = start[b], n = hist[b];
    int cnt = M_ - (int)lo - (int)n;   // everything in strictly-better buckets
    for (unsigned j = lo; j < lo + n; ++j) {
        float sc = sConf[j];
        cnt += (sc > c) || (sc == c && sIdx[j] < (unsigned)e);
    }
    tpRank[thr_i * NL_ + t] = cnt;
}

// ---- Phase 3a: position of each TP among TPs (ranks are distinct) ---------
__global__ void pos_kernel(const int* __restrict__ tpCount,
                           const int* __restrict__ tpRank,
                           int* __restrict__ sortedRank)
{
    int thr_i = blockIdx.y;
    int T = tpCount[thr_i];
    int t = blockIdx.x * blockDim.x + threadIdx.x;
    if (t >= T) return;
    int r = tpRank[thr_i * NL_ + t];
    const int* base = tpRank + thr_i * NL_;
    int p = 0;
    for (int u = 0; u < T; ++u) p += (base[u] < r);
    sortedRank[thr_i * NL_ + p] = r;
}

// ---- Phase 3b: AP from sorted TP ranks. One block per threshold. ----------
// AP = sum over TPs (sorted pos q_t >= 1) of (fl((t+1)/NL)-fl(t/NL)) * smax_t,
// smax_t = max_{u>=t} (u+1)/(q_u+1)  (f32 divisions, matching the reference).
__global__ __launch_bounds__(1024) void ap_kernel(const int* __restrict__ tpCount,
                                                  const int* __restrict__ sortedRank,
                                                  float* __restrict__ out)
{
    const int C = 13;   // 1024*13 = 13312 >= NL_
    int thr_i = blockIdx.x;
    int T = tpCount[thr_i];
    int t = threadIdx.x;
    const int* sr = sortedRank + thr_i * NL_;

    float pr[C]; int rk[C];
    #pragma unroll
    for (int k = 0; k < C; ++k) {
        int i = t * C + k;
        if (i < T) { rk[k] = sr[i]; pr[k] = (float)(i + 1) / (float)(rk[k] + 1); }
        else { rk[k] = -1; pr[k] = -1.0f; }   // precision >= 0, so -1 is neutral
    }
    float suf[C];
    float run = -1.0f;
    #pragma unroll
    for (int k = C - 1; k >= 0; --k) { run = fmaxf(run, pr[k]); suf[k] = run; }

    __shared__ float cmax[1024];
    cmax[t] = run;
    __syncthreads();
    for (int off = 1; off < 1024; off <<= 1) {   // inclusive suffix-max scan
        float v = cmax[t];
        float o = (t + off < 1024) ? cmax[t + off] : -1.0f;
        __syncthreads();
        cmax[t] = fmaxf(v, o);
        __syncthreads();
    }
    float follow = (t + 1 < 1024) ? cmax[t + 1] : -1.0f;

    double acc = 0.0;
    #pragma unroll
    for (int k = 0; k < C; ++k) {
        int i = t * C + k;
        if (i < T && rk[k] >= 1) {    // sorted position 0 is excluded by the ref curve
            float smax = fmaxf(suf[k], follow);
            float rhi = (float)(i + 1) / 12800.0f;
            float rlo = (float)i / 12800.0f;
            acc += (double)((rhi - rlo) * smax);
        }
    }
    __shared__ double red[1024];
    red[t] = acc;
    __syncthreads();
    for (int off = 512; off >= 1; off >>= 1) {
        if (t < off) red[t] += red[t + off];
        __syncthreads();
    }
    if (t == 0) out[thr_i] = (float)red[0];
}

extern "C" void kernel_launch(void* const* d_in, const int* in_sizes, int n_in,
                              void* d_out, int out_size, void* d_ws, size_t ws_size,
                              hipStream_t stream) {
    const float* scores = (const float*)d_in[0];   // [B,N]
    const float* seg    = (const float*)d_in[1];   // [B,N,2]
    const float* gts    = (const float*)d_in[2];   // [B,G,2]
    float* out = (float*)d_out;

    char* ws = (char*)d_ws;
    // layout (all offsets multiple of 256):
    int*      tpCount    = (int*)ws;                                    // 8 B (+pad)
    unsigned* hist       = (unsigned*)(ws + 256);                       // 256 KiB
    unsigned* start      = (unsigned*)(ws + 256 + 262144);              // 256 KiB
    unsigned* cursor     = (unsigned*)(ws + 256 + 2 * 262144);          // 256 KiB
    int*      tpIdx      = (int*)(ws + 256 + 3 * 262144);               // 100 KiB
    int*      tpRank     = tpIdx + 2 * NL_;                             // 100 KiB
    int*      sortedRank = tpRank + 2 * NL_;                            // 100 KiB
    float*    sConf      = (float*)(ws + 256 + 3 * 262144 + 3 * 102400);// 4 MB
    unsigned* sIdx       = (unsigned*)((char*)sConf + (size_t)M_ * 4);  // 4 MB
    (void)ws_size; (void)in_sizes; (void)n_in; (void)out_size;

    // zero tpCount + hist (ws is poisoned 0xAA before every call)
    hipMemsetAsync(ws, 0, 256 + NBKT * 4, stream);

    tp_kernel<<<512, 256, 0, stream>>>(seg, gts, tpCount, tpIdx);
    hist_kernel<<<M_ / 256, 256, 0, stream>>>(scores, hist);
    scan_kernel<<<1, 1024, 0, stream>>>(hist, start, cursor);
    scatter_kernel<<<M_ / 256, 256, 0, stream>>>(scores, cursor, sConf, sIdx);
    rank_kernel<<<dim3(NL_ / 256, 2), 256, 0, stream>>>(scores, tpCount, tpIdx,
                                                        hist, start, sConf, sIdx, tpRank);
    pos_kernel<<<dim3(NL_ / 256, 2), 256, 0, stream>>>(tpCount, tpRank, sortedRank);
    ap_kernel<<<2, 1024, 0, stream>>>(tpCount, sortedRank, out);
}

// Round 2
// 439.227 us; speedup vs baseline: 1.7556x; 1.7556x over previous
//
#include <hip/hip_runtime.h>

// AP (average precision @ IoU 0.5/0.75) for B=256, N=4000, G=50.
// Strategy: greedy TP matching per (batch,thr) -> <=12800 TP elements per thr;
// exact stable-descending-sort ranks of TPs via 65536-bucket counting sort of
// the 1.024M confidences; AP from TP ranks only (suffix-max of precision is
// attained at TP positions). No full argsort needed.
//
// R1: pos_kernel was 390us (half of total) -- latency-bound global-load loop.
//     Now stages all 12800 ranks in LDS (50KiB) + int4 broadcast reads ->
//     VALU-bound ~21us. hist folded into tp_kernel (one fewer pass/launch).

#define B_ 256
#define N_ 4000
#define G_ 50
#define M_ (B_ * N_)        // 1,024,000 proposals total
#define NL_ (B_ * G_)       // 12,800 labels total (= n_labels)
#define SLOTS 16            // ceil(N_/256)
#define NBKT 65536

__device__ __forceinline__ unsigned bucket_of(float c) {
    unsigned b = (unsigned)(c * 65536.0f);
    return b > 65535u ? 65535u : b;
}

// ---- Phase 1: greedy matching (+ histogram, thr0 blocks only). ------------
__global__ __launch_bounds__(256) void tp_kernel(
    const float* __restrict__ seg,   // [B,N,2]
    const float* __restrict__ gts,   // [B,G,2]
    const float* __restrict__ conf,  // [B,N]
    int* __restrict__ tpCount,       // [2], pre-zeroed
    int* __restrict__ tpIdx,         // [2][NL_]
    unsigned* __restrict__ hist)     // [NBKT], pre-zeroed
{
    const int tid = threadIdx.x;
    const int b = blockIdx.x & 255;
    const int thr_i = blockIdx.x >> 8;
    const float thr = thr_i ? 0.75f : 0.5f;

    // histogram contribution: thr0 blocks cover all of scores exactly once
    if (thr_i == 0) {
        const float* cb = conf + (size_t)b * N_;
        #pragma unroll
        for (int s = 0; s < SLOTS; ++s) {
            int n = s * 256 + tid;
            if (n < N_) atomicAdd(&hist[bucket_of(cb[n])], 1u);
        }
    }

    float amin[SLOTS], amax[SLOTS];
    const float2* sb = (const float2*)(seg + (size_t)b * (N_ * 2));
    #pragma unroll
    for (int s = 0; s < SLOTS; ++s) {
        int n = s * 256 + tid;
        if (n < N_) { float2 v = sb[n]; amin[s] = v.x; amax[s] = v.y; }
        else { amin[s] = 1e9f; amax[s] = 1e9f; }   // zero-length far away -> iou 0
    }

    unsigned used = 0u;
    __shared__ int lred[4];
    __shared__ int winner;
    const float* gb = gts + (size_t)b * (G_ * 2);

    for (int g = 0; g < G_; ++g) {
        float gmin = gb[2 * g], gmax = gb[2 * g + 1];
        float glen = gmax - gmin;
        int bestS = 1000;
        #pragma unroll
        for (int s = SLOTS - 1; s >= 0; --s) {   // descending: final = smallest s
            float inter = fminf(amax[s], gmax) - fmaxf(amin[s], gmin);
            inter = fmaxf(inter, 0.0f);
            float uni = (amax[s] - amin[s]) + glen - inter;  // same op order as ref
            float iou = inter / uni;
            if (!(used & (1u << s)) && iou > thr) bestS = s;
        }
        int best = (bestS < 1000) ? bestS * 256 + tid : 0x7FFFFFFF;
        #pragma unroll
        for (int off = 32; off >= 1; off >>= 1)
            best = min(best, __shfl_down(best, off, 64));
        if ((tid & 63) == 0) lred[tid >> 6] = best;
        __syncthreads();
        if (tid == 0) winner = min(min(lred[0], lred[1]), min(lred[2], lred[3]));
        __syncthreads();
        int w = winner;
        if (w != 0x7FFFFFFF && (w & 255) == tid) used |= 1u << (w >> 8);
    }

    #pragma unroll
    for (int s = 0; s < SLOTS; ++s) {
        if (used & (1u << s)) {
            int pos = atomicAdd(&tpCount[thr_i], 1);
            tpIdx[thr_i * NL_ + pos] = b * N_ + (s * 256 + tid);
        }
    }
}

// ---- Phase 2b: exclusive scan of 65536 bins, single block -----------------
__global__ __launch_bounds__(1024) void scan_kernel(
    const unsigned* __restrict__ hist, unsigned* __restrict__ start,
    unsigned* __restrict__ cursor)
{
    __shared__ unsigned part[1024];
    int t = threadIdx.x;
    unsigned loc[64];
    unsigned s = 0;
    for (int k = 0; k < 64; ++k) { loc[k] = s; s += hist[t * 64 + k]; }
    part[t] = s;
    __syncthreads();
    for (int off = 1; off < 1024; off <<= 1) {   // inclusive Hillis-Steele
        unsigned add = (t >= off) ? part[t - off] : 0u;
        unsigned v = part[t];
        __syncthreads();
        part[t] = v + add;
        __syncthreads();
    }
    unsigned base = (t == 0) ? 0u : part[t - 1];
    for (int k = 0; k < 64; ++k) {
        unsigned st = base + loc[k];
        start[t * 64 + k] = st;
        cursor[t * 64 + k] = st;
    }
}

// ---- Phase 2c: scatter into bucket-grouped order --------------------------
__global__ void scatter_kernel(const float* __restrict__ conf,
                               unsigned* __restrict__ cursor,
                               float* __restrict__ sConf,
                               unsigned* __restrict__ sIdx)
{
    int i = blockIdx.x * blockDim.x + threadIdx.x;
    if (i < M_) {
        float c = conf[i];
        unsigned b = bucket_of(c);
        unsigned pos = atomicAdd(&cursor[b], 1u);
        sConf[pos] = c;
        sIdx[pos] = (unsigned)i;
    }
}

// ---- Phase 2d: exact rank of each TP (stable descending order) ------------
__global__ void rank_kernel(const float* __restrict__ conf,
                            const int* __restrict__ tpCount,
                            const int* __restrict__ tpIdx,
                            const unsigned* __restrict__ hist,
                            const unsigned* __restrict__ start,
                            const float* __restrict__ sConf,
                            const unsigned* __restrict__ sIdx,
                            int* __restrict__ tpRank)
{
    int thr_i = blockIdx.y;
    int t = blockIdx.x * blockDim.x + threadIdx.x;
    if (t >= tpCount[thr_i]) return;
    int e = tpIdx[thr_i * NL_ + t];
    float c = conf[e];
    unsigned b = bucket_of(c);
    unsigned lo = start[b], n = hist[b];
    int cnt = M_ - (int)lo - (int)n;   // everything in strictly-better buckets
    for (unsigned j = lo; j < lo + n; ++j) {
        float sc = sConf[j];
        cnt += (sc > c) || (sc == c && sIdx[j] < (unsigned)e);
    }
    tpRank[thr_i * NL_ + t] = cnt;
}

// ---- Phase 3a: position of each TP among TPs, via LDS ---------------------
// Ranks are distinct, so p = #{ranks < r} is a bijection.
__global__ __launch_bounds__(256) void pos_kernel(
    const int* __restrict__ tpCount,
    const int* __restrict__ tpRank,
    int* __restrict__ sortedRank)
{
    __shared__ alignas(16) int lr[NL_];
    const int thr_i = blockIdx.y;
    const int T = tpCount[thr_i];
    const int* base = tpRank + thr_i * NL_;
    for (int i = threadIdx.x; i < NL_; i += 256)
        lr[i] = (i < T) ? base[i] : 0x7FFFFFFF;   // sentinel never counts as < r
    __syncthreads();

    int t = blockIdx.x * 256 + threadIdx.x;
    if (t >= T) return;
    int r = lr[t];
    int p = 0;
    const int4* l4 = (const int4*)lr;
    #pragma unroll 8
    for (int u = 0; u < NL_ / 4; ++u) {   // wave-uniform addr -> LDS broadcast
        int4 v = l4[u];
        p += (v.x < r) + (v.y < r) + (v.z < r) + (v.w < r);
    }
    sortedRank[thr_i * NL_ + p] = r;
}

// ---- Phase 3b: AP from sorted TP ranks. One block per threshold. ----------
__global__ __launch_bounds__(1024) void ap_kernel(const int* __restrict__ tpCount,
                                                  const int* __restrict__ sortedRank,
                                                  float* __restrict__ out)
{
    const int C = 13;   // 1024*13 = 13312 >= NL_
    int thr_i = blockIdx.x;
    int T = tpCount[thr_i];
    int t = threadIdx.x;
    const int* sr = sortedRank + thr_i * NL_;

    float pr[C]; int rk[C];
    #pragma unroll
    for (int k = 0; k < C; ++k) {
        int i = t * C + k;
        if (i < T) { rk[k] = sr[i]; pr[k] = (float)(i + 1) / (float)(rk[k] + 1); }
        else { rk[k] = -1; pr[k] = -1.0f; }
    }
    float suf[C];
    float run = -1.0f;
    #pragma unroll
    for (int k = C - 1; k >= 0; --k) { run = fmaxf(run, pr[k]); suf[k] = run; }

    __shared__ float cmax[1024];
    cmax[t] = run;
    __syncthreads();
    for (int off = 1; off < 1024; off <<= 1) {   // inclusive suffix-max scan
        float v = cmax[t];
        float o = (t + off < 1024) ? cmax[t + off] : -1.0f;
        __syncthreads();
        cmax[t] = fmaxf(v, o);
        __syncthreads();
    }
    float follow = (t + 1 < 1024) ? cmax[t + 1] : -1.0f;

    double acc = 0.0;
    #pragma unroll
    for (int k = 0; k < C; ++k) {
        int i = t * C + k;
        if (i < T && rk[k] >= 1) {    // sorted position 0 excluded by the ref curve
            float smax = fmaxf(suf[k], follow);
            float rhi = (float)(i + 1) / 12800.0f;
            float rlo = (float)i / 12800.0f;
            acc += (double)((rhi - rlo) * smax);
        }
    }
    __shared__ double red[1024];
    red[t] = acc;
    __syncthreads();
    for (int off = 512; off >= 1; off >>= 1) {
        if (t < off) red[t] += red[t + off];
        __syncthreads();
    }
    if (t == 0) out[thr_i] = (float)red[0];
}

extern "C" void kernel_launch(void* const* d_in, const int* in_sizes, int n_in,
                              void* d_out, int out_size, void* d_ws, size_t ws_size,
                              hipStream_t stream) {
    const float* scores = (const float*)d_in[0];   // [B,N]
    const float* seg    = (const float*)d_in[1];   // [B,N,2]
    const float* gts    = (const float*)d_in[2];   // [B,G,2]
    float* out = (float*)d_out;

    char* ws = (char*)d_ws;
    int*      tpCount    = (int*)ws;                                    // 8 B (+pad)
    unsigned* hist       = (unsigned*)(ws + 256);                       // 256 KiB
    unsigned* start      = (unsigned*)(ws + 256 + 262144);              // 256 KiB
    unsigned* cursor     = (unsigned*)(ws + 256 + 2 * 262144);          // 256 KiB
    int*      tpIdx      = (int*)(ws + 256 + 3 * 262144);               // 100 KiB
    int*      tpRank     = tpIdx + 2 * NL_;                             // 100 KiB
    int*      sortedRank = tpRank + 2 * NL_;                            // 100 KiB
    float*    sConf      = (float*)(ws + 256 + 3 * 262144 + 3 * 102400);// 4 MB
    unsigned* sIdx       = (unsigned*)((char*)sConf + (size_t)M_ * 4);  // 4 MB
    (void)ws_size; (void)in_sizes; (void)n_in; (void)out_size;

    // zero tpCount + hist (ws is poisoned 0xAA before every call)
    hipMemsetAsync(ws, 0, 256 + NBKT * 4, stream);

    tp_kernel<<<512, 256, 0, stream>>>(seg, gts, scores, tpCount, tpIdx, hist);
    scan_kernel<<<1, 1024, 0, stream>>>(hist, start, cursor);
    scatter_kernel<<<M_ / 256, 256, 0, stream>>>(scores, cursor, sConf, sIdx);
    rank_kernel<<<dim3(NL_ / 256, 2), 256, 0, stream>>>(scores, tpCount, tpIdx,
                                                        hist, start, sConf, sIdx, tpRank);
    pos_kernel<<<dim3(NL_ / 256, 2), 256, 0, stream>>>(tpCount, tpRank, sortedRank);
    ap_kernel<<<2, 1024, 0, stream>>>(tpCount, sortedRank, out);
}

// Round 3
// 429.954 us; speedup vs baseline: 1.7935x; 1.0216x over previous
//
#include <hip/hip_runtime.h>

// AP (average precision @ IoU 0.5/0.75) for B=256, N=4000, G=50.
// Strategy: greedy TP matching per (batch,thr) -> <=12800 TP elements per thr;
// exact stable-descending-sort ranks of TPs via 65536-bucket counting sort of
// the 1.024M confidences; AP from TP ranks only (suffix-max of precision is
// attained at TP positions). No full argsort needed.
//
// R1: pos_kernel 390us (latency-bound global loop) -> LDS+int4 broadcast.
// R2: tp_kernel 161us: VGPR_Count=32 + 32MB WRITE_SIZE = the amin/amax[16]
//     register arrays were spilled to scratch. Rewritten: ballot-built
//     candidate bitmasks in LDS (Phase A, no arrays, no barriers), then
//     wave-0-only bitmask greedy (Phase B, zero barriers).

#define B_ 256
#define N_ 4000
#define G_ 50
#define M_ (B_ * N_)        // 1,024,000 proposals total
#define NL_ (B_ * G_)       // 12,800 labels total (= n_labels)
#define SLOTS 16            // ceil(N_/256)
#define NBKT 65536

__device__ __forceinline__ unsigned bucket_of(float c) {
    unsigned b = (unsigned)(c * 65536.0f);
    return b > 65535u ? 65535u : b;
}

// ---- Phase 1: greedy matching (+ histogram, thr0 blocks only). ------------
__global__ __launch_bounds__(256) void tp_kernel(
    const float* __restrict__ seg,   // [B,N,2]
    const float* __restrict__ gts,   // [B,G,2]
    const float* __restrict__ conf,  // [B,N]
    int* __restrict__ tpCount,       // [2], pre-zeroed
    int* __restrict__ tpIdx,         // [2][NL_]
    unsigned* __restrict__ hist)     // [NBKT], pre-zeroed
{
    const int tid  = threadIdx.x;
    const int lane = tid & 63;
    const int wv   = tid >> 6;            // wave id 0..3
    const int b     = blockIdx.x & 255;
    const int thr_i = blockIdx.x >> 8;
    const float thr = thr_i ? 0.75f : 0.5f;

    __shared__ float2 gtl[G_];                          // 400 B
    __shared__ unsigned long long cand[G_][64];         // 50*64*8 = 25.6 KiB

    if (tid < G_) gtl[tid] = ((const float2*)gts)[b * G_ + tid];

    // histogram contribution: thr0 blocks cover all of scores exactly once
    if (thr_i == 0) {
        const float* cb = conf + (size_t)b * N_;
        #pragma unroll
        for (int s = 0; s < SLOTS; ++s) {
            int n = s * 256 + tid;
            if (n < N_) atomicAdd(&hist[bucket_of(cb[n])], 1u);
        }
    }
    __syncthreads();

    // Phase A: build per-gt candidate bitmasks via ballot. No per-thread arrays.
    const float2* sb = (const float2*)(seg + (size_t)b * (N_ * 2));
    for (int s = 0; s < SLOTS; ++s) {
        int n = s * 256 + tid;
        float pmin, pmax;
        if (n < N_) { float2 v = sb[n]; pmin = v.x; pmax = v.y; }
        else { pmin = 1e9f; pmax = 1e9f; }   // sentinel -> iou 0
        const int q = s * 4 + wv;            // qword index for this wave's 64 props
        for (int g = 0; g < G_; ++g) {
            float2 gt = gtl[g];              // LDS broadcast
            float glen = gt.y - gt.x;
            float inter = fmaxf(fminf(pmax, gt.y) - fmaxf(pmin, gt.x), 0.0f);
            float uni = (pmax - pmin) + glen - inter;   // same op order as ref
            float iou = inter / uni;
            unsigned long long m = __ballot(iou > thr);
            if (lane == 0) cand[g][q] = m;
        }
    }
    __syncthreads();

    // Phase B: wave 0 only; greedy over bitmasks, used-qword per lane in regs.
    if (wv == 0) {
        unsigned long long used = 0ull;      // proposals [lane*64, lane*64+64)
        for (int g = 0; g < G_; ++g) {
            unsigned long long c = cand[g][lane] & ~used;
            int idx = c ? (lane * 64 + __ffsll(c) - 1) : 0x7FFFFFFF;
            #pragma unroll
            for (int off = 32; off >= 1; off >>= 1)
                idx = min(idx, __shfl_down(idx, off, 64));
            int best = __shfl(idx, 0, 64);
            if (best != 0x7FFFFFFF && (best >> 6) == lane)
                used |= 1ull << (best & 63);
        }
        int c = __popcll(used);
        if (c) {
            int pos = atomicAdd(&tpCount[thr_i], c);
            unsigned long long u = used;
            while (u) {
                int bit = __ffsll(u) - 1;
                u &= u - 1;
                tpIdx[thr_i * NL_ + pos++] = b * N_ + lane * 64 + bit;
            }
        }
    }
}

// ---- Phase 2b: exclusive scan of 65536 bins, single block -----------------
__global__ __launch_bounds__(1024) void scan_kernel(
    const unsigned* __restrict__ hist, unsigned* __restrict__ start,
    unsigned* __restrict__ cursor)
{
    __shared__ unsigned part[1024];
    int t = threadIdx.x;
    unsigned loc[64];
    unsigned s = 0;
    for (int k = 0; k < 64; ++k) { loc[k] = s; s += hist[t * 64 + k]; }
    part[t] = s;
    __syncthreads();
    for (int off = 1; off < 1024; off <<= 1) {   // inclusive Hillis-Steele
        unsigned add = (t >= off) ? part[t - off] : 0u;
        unsigned v = part[t];
        __syncthreads();
        part[t] = v + add;
        __syncthreads();
    }
    unsigned base = (t == 0) ? 0u : part[t - 1];
    for (int k = 0; k < 64; ++k) {
        unsigned st = base + loc[k];
        start[t * 64 + k] = st;
        cursor[t * 64 + k] = st;
    }
}

// ---- Phase 2c: scatter into bucket-grouped order --------------------------
__global__ void scatter_kernel(const float* __restrict__ conf,
                               unsigned* __restrict__ cursor,
                               float* __restrict__ sConf,
                               unsigned* __restrict__ sIdx)
{
    int i = blockIdx.x * blockDim.x + threadIdx.x;
    if (i < M_) {
        float c = conf[i];
        unsigned b = bucket_of(c);
        unsigned pos = atomicAdd(&cursor[b], 1u);
        sConf[pos] = c;
        sIdx[pos] = (unsigned)i;
    }
}

// ---- Phase 2d: exact rank of each TP (stable descending order) ------------
__global__ void rank_kernel(const float* __restrict__ conf,
                            const int* __restrict__ tpCount,
                            const int* __restrict__ tpIdx,
                            const unsigned* __restrict__ hist,
                            const unsigned* __restrict__ start,
                            const float* __restrict__ sConf,
                            const unsigned* __restrict__ sIdx,
                            int* __restrict__ tpRank)
{
    int thr_i = blockIdx.y;
    int t = blockIdx.x * blockDim.x + threadIdx.x;
    if (t >= tpCount[thr_i]) return;
    int e = tpIdx[thr_i * NL_ + t];
    float c = conf[e];
    unsigned b = bucket_of(c);
    unsigned lo = start[b], n = hist[b];
    int cnt = M_ - (int)lo - (int)n;   // everything in strictly-better buckets
    for (unsigned j = lo; j < lo + n; ++j) {
        float sc = sConf[j];
        cnt += (sc > c) || (sc == c && sIdx[j] < (unsigned)e);
    }
    tpRank[thr_i * NL_ + t] = cnt;
}

// ---- Phase 3a: position of each TP among TPs, via LDS ---------------------
__global__ __launch_bounds__(256) void pos_kernel(
    const int* __restrict__ tpCount,
    const int* __restrict__ tpRank,
    int* __restrict__ sortedRank)
{
    __shared__ alignas(16) int lr[NL_];
    const int thr_i = blockIdx.y;
    const int T = tpCount[thr_i];
    const int* base = tpRank + thr_i * NL_;
    for (int i = threadIdx.x; i < NL_; i += 256)
        lr[i] = (i < T) ? base[i] : 0x7FFFFFFF;   // sentinel never counts as < r
    __syncthreads();

    int t = blockIdx.x * 256 + threadIdx.x;
    if (t >= T) return;
    int r = lr[t];
    int p = 0;
    const int4* l4 = (const int4*)lr;
    #pragma unroll 8
    for (int u = 0; u < NL_ / 4; ++u) {   // wave-uniform addr -> LDS broadcast
        int4 v = l4[u];
        p += (v.x < r) + (v.y < r) + (v.z < r) + (v.w < r);
    }
    sortedRank[thr_i * NL_ + p] = r;
}

// ---- Phase 3b: AP from sorted TP ranks. One block per threshold. ----------
__global__ __launch_bounds__(1024) void ap_kernel(const int* __restrict__ tpCount,
                                                  const int* __restrict__ sortedRank,
                                                  float* __restrict__ out)
{
    const int C = 13;   // 1024*13 = 13312 >= NL_
    int thr_i = blockIdx.x;
    int T = tpCount[thr_i];
    int t = threadIdx.x;
    const int* sr = sortedRank + thr_i * NL_;

    float pr[C]; int rk[C];
    #pragma unroll
    for (int k = 0; k < C; ++k) {
        int i = t * C + k;
        if (i < T) { rk[k] = sr[i]; pr[k] = (float)(i + 1) / (float)(rk[k] + 1); }
        else { rk[k] = -1; pr[k] = -1.0f; }
    }
    float suf[C];
    float run = -1.0f;
    #pragma unroll
    for (int k = C - 1; k >= 0; --k) { run = fmaxf(run, pr[k]); suf[k] = run; }

    __shared__ float cmax[1024];
    cmax[t] = run;
    __syncthreads();
    for (int off = 1; off < 1024; off <<= 1) {   // inclusive suffix-max scan
        float v = cmax[t];
        float o = (t + off < 1024) ? cmax[t + off] : -1.0f;
        __syncthreads();
        cmax[t] = fmaxf(v, o);
        __syncthreads();
    }
    float follow = (t + 1 < 1024) ? cmax[t + 1] : -1.0f;

    double acc = 0.0;
    #pragma unroll
    for (int k = 0; k < C; ++k) {
        int i = t * C + k;
        if (i < T && rk[k] >= 1) {    // sorted position 0 excluded by the ref curve
            float smax = fmaxf(suf[k], follow);
            float rhi = (float)(i + 1) / 12800.0f;
            float rlo = (float)i / 12800.0f;
            acc += (double)((rhi - rlo) * smax);
        }
    }
    __shared__ double red[1024];
    red[t] = acc;
    __syncthreads();
    for (int off = 512; off >= 1; off >>= 1) {
        if (t < off) red[t] += red[t + off];
        __syncthreads();
    }
    if (t == 0) out[thr_i] = (float)red[0];
}

extern "C" void kernel_launch(void* const* d_in, const int* in_sizes, int n_in,
                              void* d_out, int out_size, void* d_ws, size_t ws_size,
                              hipStream_t stream) {
    const float* scores = (const float*)d_in[0];   // [B,N]
    const float* seg    = (const float*)d_in[1];   // [B,N,2]
    const float* gts    = (const float*)d_in[2];   // [B,G,2]
    float* out = (float*)d_out;

    char* ws = (char*)d_ws;
    int*      tpCount    = (int*)ws;                                    // 8 B (+pad)
    unsigned* hist       = (unsigned*)(ws + 256);                       // 256 KiB
    unsigned* start      = (unsigned*)(ws + 256 + 262144);              // 256 KiB
    unsigned* cursor     = (unsigned*)(ws + 256 + 2 * 262144);          // 256 KiB
    int*      tpIdx      = (int*)(ws + 256 + 3 * 262144);               // 100 KiB
    int*      tpRank     = tpIdx + 2 * NL_;                             // 100 KiB
    int*      sortedRank = tpRank + 2 * NL_;                            // 100 KiB
    float*    sConf      = (float*)(ws + 256 + 3 * 262144 + 3 * 102400);// 4 MB
    unsigned* sIdx       = (unsigned*)((char*)sConf + (size_t)M_ * 4);  // 4 MB
    (void)ws_size; (void)in_sizes; (void)n_in; (void)out_size;

    // zero tpCount + hist (ws is poisoned 0xAA before every call)
    hipMemsetAsync(ws, 0, 256 + NBKT * 4, stream);

    tp_kernel<<<512, 256, 0, stream>>>(seg, gts, scores, tpCount, tpIdx, hist);
    scan_kernel<<<1, 1024, 0, stream>>>(hist, start, cursor);
    scatter_kernel<<<M_ / 256, 256, 0, stream>>>(scores, cursor, sConf, sIdx);
    rank_kernel<<<dim3(NL_ / 256, 2), 256, 0, stream>>>(scores, tpCount, tpIdx,
                                                        hist, start, sConf, sIdx, tpRank);
    pos_kernel<<<dim3(NL_ / 256, 2), 256, 0, stream>>>(tpCount, tpRank, sortedRank);
    ap_kernel<<<2, 1024, 0, stream>>>(tpCount, sortedRank, out);
}